// Round 9
// baseline (712.486 us; speedup 1.0000x reference)
//
#include <hip/hip_runtime.h>
#include <math.h>

// ---------------------------------------------------------------------------
// 2-layer GCN:  out = GCNConv(relu(GCNConv(x, W1, b1)), W2, b2)
// Factorization: g = (x@W) * dinv[row];  agg[d] = g[d] + sum_{s in in(d)} g[s];
//                out[d] = agg[d]*dinv[d] + b   (dinv = rsqrt(indeg+1))
//
// R1-R5: bucket sort -> LDS sort -> 16b G rows -> dwordx4 gathers (342us).
// R6-R11 locality arc: FETCH 162->63MB reachable but dur never improved ->
//   aggregate NOT BW-bound. Terminated.
// R12: fdot2 (fp16 G): VALU 50->45%, dur 58.2->57.6. -> aggregate is
//   MSHR-latency bound (410MB served @7.1TB/s ~ 64 lines x 64B / 300cy).
//   FROZEN at ~its structural limit for this shape.
// R13: the constant, INVISIBLE ~220us outside aggregate is the target.
//   bucket_bin+csr_sort (7 global + 6 LDS ops/edge, double staging) replaced
//   by flat global counting sort with computable costs:
//     hist (1 read + 1 fire-and-forget atomic /edge)      ~5us
//     3-level scan (offs/cur/dinv, hierarchical)          ~6us
//     scatter (2 reads + 1 returning atomic + 1 write)    ~15-25us
//   cnt deleted (num = offs[w+1]-offs[w]); csr dense E. agg/gemm frozen.
//   Diagnostic round: if total doesn't move, prep was never the cost ->
//   the hidden time is the gemms -> next = f16 MFMA gemm.
// R14: R13 failed to compile (csr unsigned* vs int* param). Type fixed,
//   resubmit -- theory and predictions unchanged.
// ---------------------------------------------------------------------------

typedef unsigned short ushort_t;
typedef _Float16 h2_t __attribute__((ext_vector_type(2)));
typedef _Float16 h4_t __attribute__((ext_vector_type(4)));

// ---- flat counting sort ----------------------------------------------------

__global__ __launch_bounds__(256) void hist_k(const int* __restrict__ dst,
                                              int* __restrict__ hist, int E) {
    int i = blockIdx.x * 256 + threadIdx.x;
    const int stride = gridDim.x * 256;
    for (; i < E; i += stride) atomicAdd(&hist[dst[i]], 1);   // no return: fire-and-forget
}

// per-256-block sums of hist -> bsum[nb]
__global__ __launch_bounds__(256) void scan_blk(const int* __restrict__ hist,
                                                int* __restrict__ bsum, int N) {
    __shared__ int sh[256];
    const int t = threadIdx.x;
    const int i = blockIdx.x * 256 + t;
    sh[t] = (i < N) ? hist[i] : 0;
    __syncthreads();
    for (int d = 128; d > 0; d >>= 1) {
        if (t < d) sh[t] += sh[t + d];
        __syncthreads();
    }
    if (t == 0) bsum[blockIdx.x] = sh[0];
}

// exclusive scan of bsum[nb] (nb <= 512) -> bbase
__global__ __launch_bounds__(512) void scan_top(const int* __restrict__ bsum,
                                                int* __restrict__ bbase, int nb) {
    __shared__ int sh[512];
    const int t = threadIdx.x;
    int v = (t < nb) ? bsum[t] : 0;
    sh[t] = v;
    __syncthreads();
    for (int d = 1; d < 512; d <<= 1) {
        int u = (t >= d) ? sh[t - d] : 0;
        __syncthreads();
        sh[t] += u;
        __syncthreads();
    }
    if (t < nb) bbase[t] = sh[t] - v;
}

// final: offs[i] (exclusive), cur[i] (scatter cursor copy), dinv[i], offs[N]=E
__global__ __launch_bounds__(256) void scan_fin(const int* __restrict__ hist,
                                                const int* __restrict__ bbase,
                                                int* __restrict__ offs,
                                                int* __restrict__ cur,
                                                float* __restrict__ dinv, int N) {
    __shared__ int sh[256];
    const int t = threadIdx.x;
    const int i = blockIdx.x * 256 + t;
    const int v = (i < N) ? hist[i] : 0;
    sh[t] = v;
    __syncthreads();
    for (int d = 1; d < 256; d <<= 1) {
        int u = (t >= d) ? sh[t - d] : 0;
        __syncthreads();
        sh[t] += u;
        __syncthreads();
    }
    const int ex = bbase[blockIdx.x] + sh[t] - v;   // exclusive prefix
    if (i < N) {
        offs[i] = ex;
        cur[i]  = ex;
        dinv[i] = rsqrtf((float)(v + 1));
        if (i == N - 1) offs[N] = ex + v;
    }
}

// csr[pos] = src for each edge; pos via returning atomic on cur[dst].
// Scattered 4B writes land in per-XCD L2 (csr 12.8MB), byte-mask writeback.
__global__ __launch_bounds__(256) void scatter_k(const int* __restrict__ src,
                                                 const int* __restrict__ dst,
                                                 int* __restrict__ cur,
                                                 unsigned* __restrict__ csr, int E) {
    int i = blockIdx.x * 256 + threadIdx.x;
    const int stride = gridDim.x * 256;
    for (; i < E; i += stride) {
        int s = src[i];
        int d = dst[i];
        int pos = atomicAdd(&cur[d], 1);
        csr[pos] = (unsigned)s;
    }
}

// ---- dense layers (frozen from R12) ---------------------------------------

// G[row] = fp16( (X[row] @ W) * dinv[row] ).  X:[N,K] f32, W:[K,64], G:[N,64] f16.
template <int K>
__global__ __launch_bounds__(256) void gemm_scale(const float* __restrict__ X,
                                                  const float* __restrict__ W,
                                                  const float* __restrict__ dinv,
                                                  ushort_t* __restrict__ G, int N) {
    __shared__ float Ws[K * 64];
    const int t  = threadIdx.x;
    const int r0 = blockIdx.x * 128;

    for (int i = t; i < K * 16; i += 256)
        ((float4*)Ws)[i] = ((const float4*)W)[i];

    const int cg = (t & 15) * 4;           // column group
    const int rb = r0 + (t >> 4) * 8;      // first of this thread's 8 rows

    float acc[8][4];
#pragma unroll
    for (int j = 0; j < 8; ++j) {
        acc[j][0] = 0.f; acc[j][1] = 0.f; acc[j][2] = 0.f; acc[j][3] = 0.f;
    }
    __syncthreads();

    const bool full = (rb + 8 <= N);
    for (int k = 0; k < K; k += 4) {
        float4 xr[8];
        if (full) {
#pragma unroll
            for (int j = 0; j < 8; ++j)
                xr[j] = *(const float4*)(X + (size_t)(rb + j) * K + k);
        } else {
#pragma unroll
            for (int j = 0; j < 8; ++j)
                xr[j] = (rb + j < N) ? *(const float4*)(X + (size_t)(rb + j) * K + k)
                                     : make_float4(0.f, 0.f, 0.f, 0.f);
        }
#pragma unroll
        for (int kk = 0; kk < 4; ++kk) {
            float4 w = *(const float4*)&Ws[(k + kk) * 64 + cg];
#pragma unroll
            for (int j = 0; j < 8; ++j) {
                float xv = (&xr[j].x)[kk];
                acc[j][0] = fmaf(xv, w.x, acc[j][0]);
                acc[j][1] = fmaf(xv, w.y, acc[j][1]);
                acc[j][2] = fmaf(xv, w.z, acc[j][2]);
                acc[j][3] = fmaf(xv, w.w, acc[j][3]);
            }
        }
    }

#pragma unroll
    for (int j = 0; j < 8; ++j) {
        int row = rb + j;
        if (row < N) {
            float s = dinv[row];
            h4_t o = { (_Float16)(acc[j][0] * s), (_Float16)(acc[j][1] * s),
                       (_Float16)(acc[j][2] * s), (_Float16)(acc[j][3] * s) };
            *(h4_t*)(G + (size_t)row * 64 + cg) = o;
        }
    }
}

// fp16 pair accumulate: one v_dot2_f32_f16 per column (convert+add fused).
#define B2(u) __builtin_bit_cast(h2_t, (u))
#define DOT8(v)                                                          \
    acc[0] = __builtin_amdgcn_fdot2(B2((v).x), selx, acc[0], false);     \
    acc[1] = __builtin_amdgcn_fdot2(B2((v).x), sely, acc[1], false);     \
    acc[2] = __builtin_amdgcn_fdot2(B2((v).y), selx, acc[2], false);     \
    acc[3] = __builtin_amdgcn_fdot2(B2((v).y), sely, acc[3], false);     \
    acc[4] = __builtin_amdgcn_fdot2(B2((v).z), selx, acc[4], false);     \
    acc[5] = __builtin_amdgcn_fdot2(B2((v).z), sely, acc[5], false);     \
    acc[6] = __builtin_amdgcn_fdot2(B2((v).w), selx, acc[6], false);     \
    acc[7] = __builtin_amdgcn_fdot2(B2((v).w), sely, acc[7], false);

// Wave per node; 8 edges per gather instruction, 4 gathers in flight.
// PROVEN shape (R8-R12: ~57.6us, MSHR-latency bound). cnt replaced by offs diff.
__global__ __launch_bounds__(256) void aggregate5(const ushort_t* __restrict__ G,
                                                  const int* __restrict__ offs,
                                                  const unsigned* __restrict__ csr,
                                                  const float* __restrict__ dinv,
                                                  const float* __restrict__ bias,
                                                  float* __restrict__ out, int N,
                                                  int do_relu) {
    int w    = (blockIdx.x * 256 + threadIdx.x) >> 6;
    int lane = threadIdx.x & 63;
    if (w >= N) return;
    const int grp = lane >> 3;   // which edge of the batch of 8
    const int sub = lane & 7;    // which 16B chunk of the row
    const int beg = offs[w];
    const int num = offs[w + 1] - beg;

    const h2_t selx = {(_Float16)1.0f, (_Float16)0.0f};
    const h2_t sely = {(_Float16)0.0f, (_Float16)1.0f};

    float acc[8] = {0.f, 0.f, 0.f, 0.f, 0.f, 0.f, 0.f, 0.f};
    // self-loop: group 0 only
    if (grp == 0) {
        uint4 v = *(const uint4*)(G + (size_t)w * 64 + sub * 8);
        DOT8(v);
    }

    int e = 0;
    for (; e + 32 <= num; e += 32) {
        unsigned s0 = csr[beg + e + grp];
        unsigned s1 = csr[beg + e + 8 + grp];
        unsigned s2 = csr[beg + e + 16 + grp];
        unsigned s3 = csr[beg + e + 24 + grp];
        uint4 v0 = *(const uint4*)(G + ((size_t)s0 << 6) + (sub << 3));
        uint4 v1 = *(const uint4*)(G + ((size_t)s1 << 6) + (sub << 3));
        uint4 v2 = *(const uint4*)(G + ((size_t)s2 << 6) + (sub << 3));
        uint4 v3 = *(const uint4*)(G + ((size_t)s3 << 6) + (sub << 3));
        DOT8(v0); DOT8(v1); DOT8(v2); DOT8(v3);
    }
    if (e + 16 <= num) {
        unsigned s0 = csr[beg + e + grp];
        unsigned s1 = csr[beg + e + 8 + grp];
        uint4 v0 = *(const uint4*)(G + ((size_t)s0 << 6) + (sub << 3));
        uint4 v1 = *(const uint4*)(G + ((size_t)s1 << 6) + (sub << 3));
        DOT8(v0); DOT8(v1);
        e += 16;
    }
    if (e + 8 <= num) {
        unsigned s0 = csr[beg + e + grp];
        uint4 v0 = *(const uint4*)(G + ((size_t)s0 << 6) + (sub << 3));
        DOT8(v0);
        e += 8;
    }
    int rem = num - e;
    if (grp < rem) {
        unsigned s0 = csr[beg + e + grp];
        uint4 v0 = *(const uint4*)(G + ((size_t)s0 << 6) + (sub << 3));
        DOT8(v0);
    }

    // reduce across the 8 groups (lanes sharing `sub`): xor masks 8,16,32
#pragma unroll
    for (int m = 8; m <= 32; m <<= 1) {
#pragma unroll
        for (int j = 0; j < 8; ++j) acc[j] += __shfl_xor(acc[j], m, 64);
    }

    if (grp == 0) {
        float d = dinv[w];
        float4 bl0 = *(const float4*)(bias + sub * 8);
        float4 bl1 = *(const float4*)(bias + sub * 8 + 4);
        float4 o0 = make_float4(fmaf(acc[0], d, bl0.x), fmaf(acc[1], d, bl0.y),
                                fmaf(acc[2], d, bl0.z), fmaf(acc[3], d, bl0.w));
        float4 o1 = make_float4(fmaf(acc[4], d, bl1.x), fmaf(acc[5], d, bl1.y),
                                fmaf(acc[6], d, bl1.z), fmaf(acc[7], d, bl1.w));
        if (do_relu) {
            o0.x = fmaxf(o0.x, 0.f); o0.y = fmaxf(o0.y, 0.f);
            o0.z = fmaxf(o0.z, 0.f); o0.w = fmaxf(o0.w, 0.f);
            o1.x = fmaxf(o1.x, 0.f); o1.y = fmaxf(o1.y, 0.f);
            o1.z = fmaxf(o1.z, 0.f); o1.w = fmaxf(o1.w, 0.f);
        }
        *(float4*)(out + (size_t)w * 64 + sub * 8)     = o0;
        *(float4*)(out + (size_t)w * 64 + sub * 8 + 4) = o1;
    }
}

extern "C" void kernel_launch(void* const* d_in, const int* in_sizes, int n_in,
                              void* d_out, int out_size, void* d_ws, size_t ws_size,
                              hipStream_t stream) {
    const float* x  = (const float*)d_in[0];
    const int*   ei = (const int*)d_in[1];
    const float* W1 = (const float*)d_in[2];
    const float* b1 = (const float*)d_in[3];
    const float* W2 = (const float*)d_in[4];
    const float* b2 = (const float*)d_in[5];
    float* out = (float*)d_out;

    const int IN_CH = 128;
    const int N = in_sizes[0] / IN_CH;   // 100000
    const int E = in_sizes[1] / 2;       // 3200000
    const int* src = ei;
    const int* dst = ei + E;
    const int NBLK = (N + 255) / 256;    // 391 (<= 512 for scan_top)

    char* ws = (char*)d_ws;
    size_t off = 0;
    auto take = [&](size_t bytes) -> char* {
        char* p = ws + off;
        off += (bytes + 255) & ~(size_t)255;
        return p;
    };
    float*    dinv  = (float*)take((size_t)N * 4);
    int*      hist  = (int*)take((size_t)N * 4);
    int*      offs  = (int*)take(((size_t)N + 1) * 4);
    int*      cur   = (int*)take((size_t)N * 4);
    int*      bsum  = (int*)take((size_t)NBLK * 4);
    int*      bbase = (int*)take((size_t)NBLK * 4);
    unsigned* csr   = (unsigned*)take((size_t)E * 4);         // 12.8MB dense
    ushort_t* g     = (ushort_t*)take((size_t)N * 64 * 2);    // 12.8MB
    float*    a1    = (float*)take((size_t)N * 64 * 4);       // 25.6MB

    (void)hipMemsetAsync(hist, 0, (size_t)N * 4, stream);
    hist_k<<<2048, 256, 0, stream>>>(dst, hist, E);
    scan_blk<<<NBLK, 256, 0, stream>>>(hist, bsum, N);
    scan_top<<<1, 512, 0, stream>>>(bsum, bbase, NBLK);
    scan_fin<<<NBLK, 256, 0, stream>>>(hist, bbase, offs, cur, dinv, N);
    scatter_k<<<2048, 256, 0, stream>>>(src, dst, cur, csr, E);

    // layer 1
    gemm_scale<128><<<(N + 127) / 128, 256, 0, stream>>>(x, W1, dinv, g, N);
    aggregate5<<<(N + 3) / 4, 256, 0, stream>>>(g, offs, csr, dinv, b1, a1, N, 1);
    // layer 2
    gemm_scale<64><<<(N + 127) / 128, 256, 0, stream>>>(a1, W2, dinv, g, N);
    aggregate5<<<(N + 3) / 4, 256, 0, stream>>>(g, offs, csr, dinv, b2, out, N, 0);
}

// Round 10
// 295.181 us; speedup vs baseline: 2.4137x; 2.4137x over previous
//
#include <hip/hip_runtime.h>
#include <math.h>

// ---------------------------------------------------------------------------
// 2-layer GCN:  out = GCNConv(relu(GCNConv(x, W1, b1)), W2, b2)
// Factorization: g = (x@W) * dinv[row];  agg[d] = g[d] + sum_{s in in(d)} g[s];
//                out[d] = agg[d]*dinv[d] + b   (dinv = rsqrt(indeg+1))
//
// R1-R5: bucket sort -> LDS sort -> 16b G rows -> dwordx4 gathers (342us).
// R6-R11 locality arc: FETCH reducible 162->63MB but dur never improved ->
//   aggregate NOT BW-bound (MSHR/L3-latency bound). Terminated; agg FROZEN.
// R12: fdot2 fp16 aggregate: 57.6us/agg, absmax 0.00098. Total 334.8.
// R13/R14: flat counting sort: scatter_k=300us (returning atomics + scattered
//   4B writes -> 195MB line-writeback amplification, VALU 0.25%). REVERTED.
//   Arithmetic fallout: old prep ~45us, hist_k ~55-100 -> the hidden ~150us
//   in R12 must be the two gemm_scale kernels (each just under the 57.6
//   visibility threshold). f32-VALU gemm model was wrong ~4x.
// R15: gemms -> v_mfma_f32_16x16x32_f16. Wave = 16 rows x 64 cols, A = X
//   f32->fp16 in-register, B = W transposed to LDS fp16 (pad +8: 2-way bank
//   aliasing = free), f32 acc, dinv-scaled fp16 store. ~8-12us/gemm est.
//   Precision gamble: fp16 X/W rounding -> absmax ~2-4e-3 (layout bug would
//   be O(1) -- distinguishable). Prep + aggregate reverted to R12 exactly.
// ---------------------------------------------------------------------------

#define BKT_SHIFT 9               // 512 nodes per bucket
#define BKT_NODES 512
#define NBSH      256             // >= bucket count (196)
#define CHUNK     8192            // edges per bucket_bin block
#define MAXB      20480           // fixed per-bucket region (mean ~16.3k, 32 sigma)

typedef unsigned short ushort_t;
typedef _Float16 h2_t __attribute__((ext_vector_type(2)));
typedef _Float16 h8_t __attribute__((ext_vector_type(8)));
typedef float    f4_t __attribute__((ext_vector_type(4)));

// Phase A: bin edges into fixed-stride bucket regions (pairs[b*MAXB ...]).
// Packed pair: (dst&511)<<17 | src  (src < 2^17). bcur = per-bucket cursor.
__global__ __launch_bounds__(256) void bucket_bin(const int* __restrict__ src,
                                                  const int* __restrict__ dst,
                                                  int* __restrict__ bcur,
                                                  unsigned* __restrict__ pairs,
                                                  int E, int NB) {
    __shared__ unsigned stag[CHUNK];   // 32KB
    __shared__ int hist[NBSH];
    __shared__ int lofs[NBSH];
    __shared__ int lcur[NBSH];
    __shared__ int gbase[NBSH];
    const int t  = threadIdx.x;
    const int e0 = blockIdx.x * CHUNK;
    const int n  = min(CHUNK, E - e0);

    for (int i = t; i < NBSH; i += 256) hist[i] = 0;
    __syncthreads();
    for (int i = t; i < n; i += 256) atomicAdd(&hist[dst[e0 + i] >> BKT_SHIFT], 1);
    __syncthreads();
    int v = hist[t];
    lofs[t] = v;
    __syncthreads();
    for (int d = 1; d < 256; d <<= 1) {
        int u = (t >= d) ? lofs[t - d] : 0;
        __syncthreads();
        lofs[t] += u;
        __syncthreads();
    }
    if (t < NB) {
        lcur[t]  = lofs[t] - v;
        gbase[t] = (v > 0) ? t * MAXB + atomicAdd(&bcur[t], v) : 0;
    }
    __syncthreads();
    for (int i = t; i < n; i += 256) {
        int d = dst[e0 + i];
        int s = src[e0 + i];
        int b = d >> BKT_SHIFT;
        int p = atomicAdd(&lcur[b], 1);
        stag[p] = ((unsigned)(d & (BKT_NODES - 1)) << 17) | (unsigned)s;
    }
    __syncthreads();
    // copy-out: wave-per-bucket (parallel across the 4 waves, 64-lane runs)
    const int wv = t >> 6, ln = t & 63;
    for (int b = wv; b < NB; b += 4) {
        int cb = hist[b];
        if (cb == 0) continue;
        int lo = lofs[b] - cb;
        int gb = gbase[b];
        int lim = min(cb, (b + 1) * MAXB - gb);   // overflow clamp (never in practice)
        for (int i = ln; i < lim; i += 64) pairs[gb + i] = stag[lo + i];
    }
}

// Phase B: per-bucket 512-bin counting sort by dst node. Emits per-node
// contiguous csr lists (src values), cnt/offs/dinv. Int LDS atomics only.
__global__ __launch_bounds__(1024) void csr_sort(const unsigned* __restrict__ pairs,
                                                 const int* __restrict__ bcur,
                                                 unsigned* __restrict__ csr,
                                                 int* __restrict__ cnt,
                                                 int* __restrict__ offs,
                                                 float* __restrict__ dinv, int N) {
    extern __shared__ unsigned st[];   // MAXB entries (80KB)
    __shared__ int h[BKT_NODES];
    __shared__ int sc[BKT_NODES];
    __shared__ int cur[BKT_NODES];
    const int b    = blockIdx.x;
    const int t    = threadIdx.x;
    const int n0   = b << BKT_SHIFT;
    const int base = b * MAXB;
    const int ne   = min(bcur[b], MAXB);

    if (t < BKT_NODES) h[t] = 0;
    __syncthreads();
    for (int i = t; i < ne; i += 1024) atomicAdd(&h[pairs[base + i] >> 17], 1);
    __syncthreads();
    int v = 0;
    if (t < BKT_NODES) { v = h[t]; sc[t] = v; }
    __syncthreads();
    for (int d = 1; d < BKT_NODES; d <<= 1) {
        int u = (t < BKT_NODES && t >= d) ? sc[t - d] : 0;
        __syncthreads();
        if (t < BKT_NODES) sc[t] += u;
        __syncthreads();
    }
    if (t < BKT_NODES) {
        int ex = sc[t] - v;   // exclusive
        cur[t] = ex;
        int node = n0 + t;
        if (node < N) {
            cnt[node]  = v;
            offs[node] = base + ex;
            dinv[node] = rsqrtf((float)(v + 1));
        }
    }
    __syncthreads();
    for (int i = t; i < ne; i += 1024) {
        unsigned p = pairs[base + i];
        int pos = atomicAdd(&cur[p >> 17], 1);
        st[pos] = p & 0x1FFFFu;
    }
    __syncthreads();
    for (int i = t; i < ne; i += 1024) csr[base + i] = st[i];
}

// G[row] = fp16( (X[row] @ W) * dinv[row] ) via v_mfma_f32_16x16x32_f16.
// Block = 4 waves x 16 rows = 64 rows. A: X rows f32->f16 in-register
// (lane: row=ln&15, k=(ln>>4)*8..+7). B: Wt[64][K+8] f16 in LDS (lane:
// col=ln&15, same k -> one 16B read, pad +8 -> 2-way bank alias = free).
// C/D: col=ln&15, row=(ln>>4)*4+reg (m89-verified layout).
template <int K>
__global__ __launch_bounds__(256) void gemm_mfma(const float* __restrict__ X,
                                                 const float* __restrict__ W,
                                                 const float* __restrict__ dinv,
                                                 ushort_t* __restrict__ G, int N) {
    __shared__ _Float16 Wt[64][K + 8];
    const int t  = threadIdx.x;
    const int wv = t >> 6, ln = t & 63;
    const int rbase = blockIdx.x * 64 + wv * 16;

    // stage W[K][64] f32 -> Wt[c][k] f16 (transposed)
    for (int i = t; i < K * 16; i += 256) {
        int k  = i >> 4;
        int c4 = (i & 15) * 4;
        float4 w = ((const float4*)W)[i];
        Wt[c4 + 0][k] = (_Float16)w.x;
        Wt[c4 + 1][k] = (_Float16)w.y;
        Wt[c4 + 2][k] = (_Float16)w.z;
        Wt[c4 + 3][k] = (_Float16)w.w;
    }
    __syncthreads();

    const int row  = rbase + (ln & 15);
    const int kgrp = (ln >> 4) * 8;
    const bool rok = (row < N);

    f4_t acc[4];
#pragma unroll
    for (int c = 0; c < 4; ++c) acc[c] = (f4_t){0.f, 0.f, 0.f, 0.f};

    for (int kk = 0; kk < K; kk += 32) {
        h8_t a;
        if (rok) {
            float4 x0 = *(const float4*)(X + (size_t)row * K + kk + kgrp);
            float4 x1 = *(const float4*)(X + (size_t)row * K + kk + kgrp + 4);
            a[0] = (_Float16)x0.x; a[1] = (_Float16)x0.y;
            a[2] = (_Float16)x0.z; a[3] = (_Float16)x0.w;
            a[4] = (_Float16)x1.x; a[5] = (_Float16)x1.y;
            a[6] = (_Float16)x1.z; a[7] = (_Float16)x1.w;
        } else {
#pragma unroll
            for (int j = 0; j < 8; ++j) a[j] = (_Float16)0.0f;
        }
#pragma unroll
        for (int c = 0; c < 4; ++c) {
            h8_t b = *(const h8_t*)&Wt[c * 16 + (ln & 15)][kk + kgrp];
            acc[c] = __builtin_amdgcn_mfma_f32_16x16x32_f16(a, b, acc[c], 0, 0, 0);
        }
    }

    // epilogue: lane owns rows rbase+(ln>>4)*4+r, col c*16+(ln&15)
    _Float16* Gh = (_Float16*)G;
#pragma unroll
    for (int r = 0; r < 4; ++r) {
        int rn = rbase + ((ln >> 4) << 2) + r;
        if (rn < N) {
            float dv = dinv[rn];
#pragma unroll
            for (int c = 0; c < 4; ++c)
                Gh[(size_t)rn * 64 + c * 16 + (ln & 15)] = (_Float16)(acc[c][r] * dv);
        }
    }
}

// fp16 pair accumulate: one v_dot2_f32_f16 per column (convert+add fused).
#define B2(u) __builtin_bit_cast(h2_t, (u))
#define DOT8(v)                                                          \
    acc[0] = __builtin_amdgcn_fdot2(B2((v).x), selx, acc[0], false);     \
    acc[1] = __builtin_amdgcn_fdot2(B2((v).x), sely, acc[1], false);     \
    acc[2] = __builtin_amdgcn_fdot2(B2((v).y), selx, acc[2], false);     \
    acc[3] = __builtin_amdgcn_fdot2(B2((v).y), sely, acc[3], false);     \
    acc[4] = __builtin_amdgcn_fdot2(B2((v).z), selx, acc[4], false);     \
    acc[5] = __builtin_amdgcn_fdot2(B2((v).z), sely, acc[5], false);     \
    acc[6] = __builtin_amdgcn_fdot2(B2((v).w), selx, acc[6], false);     \
    acc[7] = __builtin_amdgcn_fdot2(B2((v).w), sely, acc[7], false);

// Wave per node; 8 edges per gather instruction, 4 gathers in flight.
// PROVEN shape (R8-R12: ~57.6us, MSHR-latency bound). Unchanged from R12.
__global__ __launch_bounds__(256) void aggregate5(const ushort_t* __restrict__ G,
                                                  const int* __restrict__ offs,
                                                  const int* __restrict__ cnt,
                                                  const unsigned* __restrict__ csr,
                                                  const float* __restrict__ dinv,
                                                  const float* __restrict__ bias,
                                                  float* __restrict__ out, int N,
                                                  int do_relu) {
    int w    = (blockIdx.x * 256 + threadIdx.x) >> 6;
    int lane = threadIdx.x & 63;
    if (w >= N) return;
    const int grp = lane >> 3;   // which edge of the batch of 8
    const int sub = lane & 7;    // which 16B chunk of the row
    const int beg = offs[w];
    const int num = cnt[w];

    const h2_t selx = {(_Float16)1.0f, (_Float16)0.0f};
    const h2_t sely = {(_Float16)0.0f, (_Float16)1.0f};

    float acc[8] = {0.f, 0.f, 0.f, 0.f, 0.f, 0.f, 0.f, 0.f};
    // self-loop: group 0 only
    if (grp == 0) {
        uint4 v = *(const uint4*)(G + (size_t)w * 64 + sub * 8);
        DOT8(v);
    }

    int e = 0;
    for (; e + 32 <= num; e += 32) {
        unsigned s0 = csr[beg + e + grp];
        unsigned s1 = csr[beg + e + 8 + grp];
        unsigned s2 = csr[beg + e + 16 + grp];
        unsigned s3 = csr[beg + e + 24 + grp];
        uint4 v0 = *(const uint4*)(G + ((size_t)s0 << 6) + (sub << 3));
        uint4 v1 = *(const uint4*)(G + ((size_t)s1 << 6) + (sub << 3));
        uint4 v2 = *(const uint4*)(G + ((size_t)s2 << 6) + (sub << 3));
        uint4 v3 = *(const uint4*)(G + ((size_t)s3 << 6) + (sub << 3));
        DOT8(v0); DOT8(v1); DOT8(v2); DOT8(v3);
    }
    if (e + 16 <= num) {
        unsigned s0 = csr[beg + e + grp];
        unsigned s1 = csr[beg + e + 8 + grp];
        uint4 v0 = *(const uint4*)(G + ((size_t)s0 << 6) + (sub << 3));
        uint4 v1 = *(const uint4*)(G + ((size_t)s1 << 6) + (sub << 3));
        DOT8(v0); DOT8(v1);
        e += 16;
    }
    if (e + 8 <= num) {
        unsigned s0 = csr[beg + e + grp];
        uint4 v0 = *(const uint4*)(G + ((size_t)s0 << 6) + (sub << 3));
        DOT8(v0);
        e += 8;
    }
    int rem = num - e;
    if (grp < rem) {
        unsigned s0 = csr[beg + e + grp];
        uint4 v0 = *(const uint4*)(G + ((size_t)s0 << 6) + (sub << 3));
        DOT8(v0);
    }

    // reduce across the 8 groups (lanes sharing `sub`): xor masks 8,16,32
#pragma unroll
    for (int m = 8; m <= 32; m <<= 1) {
#pragma unroll
        for (int j = 0; j < 8; ++j) acc[j] += __shfl_xor(acc[j], m, 64);
    }

    if (grp == 0) {
        float d = dinv[w];
        float4 bl0 = *(const float4*)(bias + sub * 8);
        float4 bl1 = *(const float4*)(bias + sub * 8 + 4);
        float4 o0 = make_float4(fmaf(acc[0], d, bl0.x), fmaf(acc[1], d, bl0.y),
                                fmaf(acc[2], d, bl0.z), fmaf(acc[3], d, bl0.w));
        float4 o1 = make_float4(fmaf(acc[4], d, bl1.x), fmaf(acc[5], d, bl1.y),
                                fmaf(acc[6], d, bl1.z), fmaf(acc[7], d, bl1.w));
        if (do_relu) {
            o0.x = fmaxf(o0.x, 0.f); o0.y = fmaxf(o0.y, 0.f);
            o0.z = fmaxf(o0.z, 0.f); o0.w = fmaxf(o0.w, 0.f);
            o1.x = fmaxf(o1.x, 0.f); o1.y = fmaxf(o1.y, 0.f);
            o1.z = fmaxf(o1.z, 0.f); o1.w = fmaxf(o1.w, 0.f);
        }
        *(float4*)(out + (size_t)w * 64 + sub * 8)     = o0;
        *(float4*)(out + (size_t)w * 64 + sub * 8 + 4) = o1;
    }
}

extern "C" void kernel_launch(void* const* d_in, const int* in_sizes, int n_in,
                              void* d_out, int out_size, void* d_ws, size_t ws_size,
                              hipStream_t stream) {
    const float* x  = (const float*)d_in[0];
    const int*   ei = (const int*)d_in[1];
    const float* W1 = (const float*)d_in[2];
    const float* b1 = (const float*)d_in[3];
    const float* W2 = (const float*)d_in[4];
    const float* b2 = (const float*)d_in[5];
    float* out = (float*)d_out;

    const int IN_CH = 128;
    const int N = in_sizes[0] / IN_CH;   // 100000
    const int E = in_sizes[1] / 2;       // 3200000
    const int* src = ei;
    const int* dst = ei + E;
    const int NB = (N + BKT_NODES - 1) >> BKT_SHIFT;  // 196

    char* ws = (char*)d_ws;
    size_t off = 0;
    auto take = [&](size_t bytes) -> char* {
        char* p = ws + off;
        off += (bytes + 255) & ~(size_t)255;
        return p;
    };
    float*    dinv  = (float*)take((size_t)N * 4);
    int*      cnt   = (int*)take((size_t)N * 4);
    int*      offs  = (int*)take((size_t)N * 4);
    int*      bcur  = (int*)take(NBSH * 4);
    unsigned* csr   = (unsigned*)take(((size_t)NB * MAXB + 64) * 4);  // 16.06MB
    ushort_t* g     = (ushort_t*)take((size_t)N * 64 * 2);            // 12.8MB
    float*    a1    = (float*)take((size_t)N * 64 * 4);               // 25.6MB
    unsigned* pairs = (unsigned*)a1;   // NB*MAXB*4 <= N*64*4; dead before agg1 writes a1

    const int nbC = (E + CHUNK - 1) / CHUNK;
    const int nbG = (N + 63) / 64;     // gemm_mfma blocks (64 rows each)

    (void)hipMemsetAsync(bcur, 0, NBSH * 4, stream);
    bucket_bin<<<nbC, 256, 0, stream>>>(src, dst, bcur, pairs, E, NB);
    csr_sort<<<NB, 1024, MAXB * 4, stream>>>(pairs, bcur, csr, cnt, offs, dinv, N);

    // layer 1
    gemm_mfma<128><<<nbG, 256, 0, stream>>>(x, W1, dinv, g, N);
    aggregate5<<<(N + 3) / 4, 256, 0, stream>>>(g, offs, cnt, csr, dinv, b1, a1, N, 1);
    // layer 2
    gemm_mfma<64><<<nbG, 256, 0, stream>>>(a1, W2, dinv, g, N);
    aggregate5<<<(N + 3) / 4, 256, 0, stream>>>(g, offs, cnt, csr, dinv, b2, out, N, 0);
}